// Round 13
// baseline (374.332 us; speedup 1.0000x reference)
//
#include <hip/hip_runtime.h>

#define Tn 200
#define Dn 64
#define Hn 64
#define CC 16   // chunk size for fallback kernel

typedef _Float16 half2v __attribute__((ext_vector_type(2)));
typedef _Float16 half8v __attribute__((ext_vector_type(8)));
typedef float    f32x4  __attribute__((ext_vector_type(4)));
typedef unsigned int uint;

__device__ __forceinline__ float fast_sigmoid(float v) {
    return __builtin_amdgcn_rcpf(1.0f + __expf(-v));
}
__device__ __forceinline__ float fast_tanh(float v) {
    return 1.0f - 2.0f * __builtin_amdgcn_rcpf(1.0f + __expf(2.0f * v));
}
// Compiler-only fence (R7-verified): intra-wave DS ordering is HW in-order.
__device__ __forceinline__ void cfence() {
    asm volatile("" ::: "memory");
}
// Full fence for the multi-wave fallback kernel (cross-wave LDS ordering).
__device__ __forceinline__ void wave_lds_fence() {
    asm volatile("s_waitcnt lgkmcnt(0)" ::: "memory");
}

__device__ __forceinline__ half8v cvt8(const float4 a, const float4 b) {
    return half8v{(_Float16)a.x, (_Float16)a.y, (_Float16)a.z, (_Float16)a.w,
                  (_Float16)b.x, (_Float16)b.y, (_Float16)b.z, (_Float16)b.w};
}

// ============================================================================
// Kernel 1 (R13): x-projection GEMM, one WAVE per 16-row subtile.
// R12 post-mortem: coalesced stores were NEUTRAL (~93 us both ways). New
// theory: cost = per-wave weight-init (192 gather loads) amortized over only
// ~3 subtiles + serial A-load latency gating every subtile. R13: grid 2048
// (12.5 subtiles/wave, 4x better init amortization, fully resident) and a
// 1-deep A-prefetch pipeline (issue next subtile's 4 global loads before
// computing the current -> load latency hides under MFMA+LDS+stores).
// ============================================================================
__global__ __launch_bounds__(64, 1)
void augru_proj_mfma(const float* __restrict__ x,     // [B*T, 64]
                     const int*   __restrict__ slen,  // [B]
                     const float* __restrict__ gk,    // [128][128]
                     const float* __restrict__ gb,    // [128]
                     const float* __restrict__ ck,    // [128][64]
                     const float* __restrict__ cb,    // [64]
                     _Float16*    __restrict__ P,     // [B*T, 192] fp16
                     int nsub)                        // nrows / 16
{
    const int lane = threadIdx.x;
    const int lm   = lane & 15;     // M (A) / N (B) index inside fragment
    const int kq   = lane >> 4;     // K quadrant
    const int G    = gridDim.x;

    __shared__ __align__(16) _Float16 sbuf[16][200];  // 6.4 KB, 400B row stride

    // ---- persistent B-frags + biases: 12 col-tiles x 2 K-halves ----
    half8v bf[12][2];
    float  bias[12];
#pragma unroll
    for (int nt = 0; nt < 12; ++nt) {
        const int n = nt * 16 + lm;
#pragma unroll
        for (int kh = 0; kh < 2; ++kh) {
            half8v f;
#pragma unroll
            for (int e = 0; e < 8; ++e) {
                const int k = kh * 32 + kq * 8 + e;
                f[e] = (_Float16)((n < 128) ? gk[k * 128 + n]
                                            : ck[k * 64 + (n - 128)]);
            }
            bf[nt][kh] = f;
        }
        bias[nt] = (n < 128) ? gb[n] : cb[n - 128];
    }

    // ---- prologue: load A for first assigned subtile ----
    float4 qa0{}, qa1{}, qa2{}, qa3{};
    if (blockIdx.x < nsub) {
        const float* xr = x + (size_t)(blockIdx.x * 16 + lm) * Dn + kq * 8;
        qa0 = *(const float4*)(xr);
        qa1 = *(const float4*)(xr + 4);
        qa2 = *(const float4*)(xr + 32);
        qa3 = *(const float4*)(xr + 36);
    }

    for (int s = blockIdx.x; s < nsub; s += G) {
        // ---- issue next subtile's A loads (1-deep pipeline) ----
        float4 qb0{}, qb1{}, qb2{}, qb3{};
        const int sn = s + G;
        if (sn < nsub) {
            const float* xr = x + (size_t)(sn * 16 + lm) * Dn + kq * 8;
            qb0 = *(const float4*)(xr);
            qb1 = *(const float4*)(xr + 4);
            qb2 = *(const float4*)(xr + 32);
            qb3 = *(const float4*)(xr + 36);
        }

        // ---- subtile validity (lane lm checks row rb+lm) ----
        const int rb   = s * 16;
        const int rowv = rb + lm;
        const int bv   = rowv / Tn;
        const int tv   = rowv - bv * Tn;
        if (__ballot(tv < slen[bv]) != 0ull) {
            const half8v a0 = cvt8(qa0, qa1);   // k = 0..31
            const half8v a1 = cvt8(qa2, qa3);   // k = 32..63

            // MFMA all 12 tiles; fragments -> LDS (row=kq*4+r, col=nt*16+lm)
#pragma unroll
            for (int nt = 0; nt < 12; ++nt) {
                f32x4 c = {bias[nt], bias[nt], bias[nt], bias[nt]};
                c = __builtin_amdgcn_mfma_f32_16x16x32_f16(a0, bf[nt][0], c, 0, 0, 0);
                c = __builtin_amdgcn_mfma_f32_16x16x32_f16(a1, bf[nt][1], c, 0, 0, 0);
#pragma unroll
                for (int r = 0; r < 4; ++r)
                    sbuf[kq * 4 + r][nt * 16 + lm] = (_Float16)c[r];
            }
            cfence();   // same-wave DS in-order; pin compiler order

            // coalesced store: 6 x dwordx4 per lane (16 rows x 384 B)
#pragma unroll
            for (int i = 0; i < 6; ++i) {
                const int idx = i * 64 + lane;   // 0..383
                const int row = idx / 24;        // 24 x 16B chunks per row
                const int c16 = idx % 24;
                const uint4 v = *(const uint4*)&sbuf[row][c16 * 8];
                *(uint4*)(P + (size_t)(rb + row) * 192 + c16 * 8) = v;
            }
            cfence();   // WAR vs next subtile's LDS writes (in-order pipe)
        }

        qa0 = qb0; qa1 = qb1; qa2 = qb2; qa3 = qb3;
    }
}

// ============================================================================
// Kernel 2 (R13): recurrence, 1 wave per row. Changes vs R7/R12:
//  - h-vectors hoisted into NAMED registers before the s_rh fence (the
//    memory-clobber fence would otherwise force LDS re-reads for u)
//  - 32 u-dots moved AFTER the s_rh write: they execute under the rh
//    write->read LDS round trip (unblocked by cfence-only discipline --
//    R2's version of this was nullified by its lgkmcnt(0) fences)
//  - 4 accumulator chains per gate (dep chain 16 -> 8)
// ============================================================================
__global__ __launch_bounds__(64, 2)
void augru_rec(const _Float16* __restrict__ P,   // [B,T,3,64] fp16
               const int*     __restrict__ slen, // [B]
               const float*   __restrict__ att,  // [B,T]
               const float*   __restrict__ gk,   // [128][128]
               const float*   __restrict__ ck,   // [128][64]
               float*         __restrict__ out)  // [B,T,H]
{
    const int b = blockIdx.x;
    const int j = threadIdx.x;

    __shared__ __align__(16) _Float16 s_h[Hn];
    __shared__ __align__(16) _Float16 s_rh[Hn];

    half2v wr[32], wu[32], wc[32];   // h-part weight cols (K rows 64..127)
#pragma unroll
    for (int m = 0; m < 32; ++m) {
        const int k = 64 + 2 * m;
        wr[m] = half2v{(_Float16)gk[(k + 0) * 128 + j],
                       (_Float16)gk[(k + 1) * 128 + j]};
        wu[m] = half2v{(_Float16)gk[(k + 0) * 128 + 64 + j],
                       (_Float16)gk[(k + 1) * 128 + 64 + j]};
        wc[m] = half2v{(_Float16)ck[(k + 0) * 64 + j],
                       (_Float16)ck[(k + 1) * 64 + j]};
    }

    const int len = slen[b];
    const _Float16* Prow = P   + (size_t)b * Tn * 192;
    const float*    arow = att + (size_t)b * Tn;
    float*          orow = out + (size_t)b * Tn * Hn;

    float h = 0.0f;

    _Float16 pr_n = (_Float16)0, pu_n = (_Float16)0, pc_n = (_Float16)0;
    float a_n = 0.0f;
    if (len > 0) {
        pr_n = Prow[j]; pu_n = Prow[64 + j]; pc_n = Prow[128 + j];
        a_n  = arow[0];
    }

    for (int t = 0; t < len; ++t) {
        const float pr = (float)pr_n;    // loaded last iteration
        const float pu = (float)pu_n;
        const float pc = (float)pc_n;
        const float a  = a_n;
        const int tn = min(t + 1, len - 1);
        const _Float16* Pt = Prow + (size_t)tn * 192;
        pr_n = Pt[j]; pu_n = Pt[64 + j]; pc_n = Pt[128 + j];
        a_n  = arow[tn];

        s_h[j] = (_Float16)h;
        cfence();   // order only; HW DS pipe is in-order within the wave

        // hoist all 8 h-vectors into named regs (live across the next fence)
        const half8v* hv = (const half8v*)s_h;
        const half8v v0 = hv[0], v1 = hv[1], v2 = hv[2], v3 = hv[3];
        const half8v v4 = hv[4], v5 = hv[5], v6 = hv[6], v7 = hv[7];

        // ---- r gate: 4 chains, 32 dots ----
        float r0 = pr, r1 = 0.f, r2 = 0.f, r3 = 0.f;
#define RDOT(v, m)                                                        \
        {   const half2v p0 = __builtin_shufflevector(v, v, 0, 1);        \
            const half2v p1 = __builtin_shufflevector(v, v, 2, 3);        \
            const half2v p2 = __builtin_shufflevector(v, v, 4, 5);        \
            const half2v p3 = __builtin_shufflevector(v, v, 6, 7);        \
            r0 = __builtin_amdgcn_fdot2(p0, wr[m + 0], r0, false);        \
            r1 = __builtin_amdgcn_fdot2(p1, wr[m + 1], r1, false);        \
            r2 = __builtin_amdgcn_fdot2(p2, wr[m + 2], r2, false);        \
            r3 = __builtin_amdgcn_fdot2(p3, wr[m + 3], r3, false);        }
        RDOT(v0, 0)  RDOT(v1, 4)  RDOT(v2, 8)  RDOT(v3, 12)
        RDOT(v4, 16) RDOT(v5, 20) RDOT(v6, 24) RDOT(v7, 28)
#undef RDOT
        const float rg = fast_sigmoid((r0 + r1) + (r2 + r3));

        // write r*h early; u-dots below run under the LDS round trip
        s_rh[j] = (_Float16)(rg * h);
        cfence();

        // ---- u gate from register copies of h ----
        float u0 = pu, u1 = 0.f, u2 = 0.f, u3 = 0.f;
#define UDOT(v, m)                                                        \
        {   const half2v p0 = __builtin_shufflevector(v, v, 0, 1);        \
            const half2v p1 = __builtin_shufflevector(v, v, 2, 3);        \
            const half2v p2 = __builtin_shufflevector(v, v, 4, 5);        \
            const half2v p3 = __builtin_shufflevector(v, v, 6, 7);        \
            u0 = __builtin_amdgcn_fdot2(p0, wu[m + 0], u0, false);        \
            u1 = __builtin_amdgcn_fdot2(p1, wu[m + 1], u1, false);        \
            u2 = __builtin_amdgcn_fdot2(p2, wu[m + 2], u2, false);        \
            u3 = __builtin_amdgcn_fdot2(p3, wu[m + 3], u3, false);        }
        UDOT(v0, 0)  UDOT(v1, 4)  UDOT(v2, 8)  UDOT(v3, 12)
        UDOT(v4, 16) UDOT(v5, 20) UDOT(v6, 24) UDOT(v7, 28)
#undef UDOT
        const float ug = fast_sigmoid((u0 + u1) + (u2 + u3));
        const float uh = (1.0f - a) * ug;

        // ---- candidate ----
        float c0 = pc, c1 = 0.f, c2 = 0.f, c3 = 0.f;
        const half8v* rv = (const half8v*)s_rh;
#pragma unroll
        for (int m8 = 0; m8 < 8; ++m8) {
            const half8v v = rv[m8];
            const half2v p0 = __builtin_shufflevector(v, v, 0, 1);
            const half2v p1 = __builtin_shufflevector(v, v, 2, 3);
            const half2v p2 = __builtin_shufflevector(v, v, 4, 5);
            const half2v p3 = __builtin_shufflevector(v, v, 6, 7);
            const int m = m8 * 4;
            c0 = __builtin_amdgcn_fdot2(p0, wc[m + 0], c0, false);
            c1 = __builtin_amdgcn_fdot2(p1, wc[m + 1], c1, false);
            c2 = __builtin_amdgcn_fdot2(p2, wc[m + 2], c2, false);
            c3 = __builtin_amdgcn_fdot2(p3, wc[m + 3], c3, false);
        }
        const float cg = fast_tanh((c0 + c1) + (c2 + c3));

        h = uh * h + (1.0f - uh) * cg;
        orow[t * Hn + j] = h;
        cfence();   // WAR vs next t's s_h/s_rh writes: HW in-order, compiler pinned
    }

    // ---- zero tail: out[b, len:T, :] = 0 ----
    float4 z;
    z.x = z.y = z.z = z.w = 0.0f;
    float* tail = orow + (size_t)len * Hn;
    const int total = (Tn - len) * Hn;
    for (int i = j * 4; i < total; i += 64 * 4) {
        *(float4*)(tail + i) = z;
    }
}

// ============================================================================
// Fallback (fused) if ws is too small for P. (unchanged)
// ============================================================================
__global__ __launch_bounds__(128, 2)
void augru_fused_fb(const float* __restrict__ x, const int* __restrict__ slen,
                    const float* __restrict__ att, const float* __restrict__ gk,
                    const float* __restrict__ gb, const float* __restrict__ ck,
                    const float* __restrict__ cb, float* __restrict__ out)
{
    const int b    = blockIdx.x;
    const int tid  = threadIdx.x;
    const int wave = tid >> 6;
    const int j    = tid & 63;

    __shared__ float s_P[2][CC][3][Hn];
    __shared__ __align__(16) _Float16 s_h[Hn];
    __shared__ __align__(16) _Float16 s_rh[Hn];

    const int len     = slen[b];
    const int nchunks = (len + CC - 1) / CC;
    const float* xrow = x   + (size_t)b * Tn * Dn;
    const float* arow = att + (size_t)b * Tn;
    float*       orow = out + (size_t)b * Tn * Hn;

    if (wave == 0) {
        half2v wr[32], wu[32], wc[32];
#pragma unroll
        for (int m = 0; m < 32; ++m) {
            const int k = 2 * m;
            wr[m] = half2v{(_Float16)gk[(k + 0) * 128 + j], (_Float16)gk[(k + 1) * 128 + j]};
            wu[m] = half2v{(_Float16)gk[(k + 0) * 128 + 64 + j], (_Float16)gk[(k + 1) * 128 + 64 + j]};
            wc[m] = half2v{(_Float16)ck[(k + 0) * 64 + j], (_Float16)ck[(k + 1) * 64 + j]};
        }
        const float br = gb[j], bu = gb[64 + j], bc = cb[j];
        for (int c = 0; c < nchunks; ++c) {
            const int t0 = c * CC, tend = min(len, t0 + CC);
            for (int t = t0; t < tend; ++t) {
                const float4* xv = (const float4*)(xrow + t * Dn);
                float r0 = br, r1 = 0.f, u0 = bu, u1 = 0.f, c0 = bc, c1 = 0.f;
#pragma unroll
                for (int kk = 0; kk < 16; ++kk) {
                    const float4 q = xv[kk];
                    const half2v p0 = half2v{(_Float16)q.x, (_Float16)q.y};
                    const half2v p1 = half2v{(_Float16)q.z, (_Float16)q.w};
                    const int m = 2 * kk;
                    r0 = __builtin_amdgcn_fdot2(p0, wr[m], r0, false);
                    r1 = __builtin_amdgcn_fdot2(p1, wr[m + 1], r1, false);
                    u0 = __builtin_amdgcn_fdot2(p0, wu[m], u0, false);
                    u1 = __builtin_amdgcn_fdot2(p1, wu[m + 1], u1, false);
                    c0 = __builtin_amdgcn_fdot2(p0, wc[m], c0, false);
                    c1 = __builtin_amdgcn_fdot2(p1, wc[m + 1], c1, false);
                }
                const int lt = t - t0;
                s_P[c & 1][lt][0][j] = r0 + r1;
                s_P[c & 1][lt][1][j] = u0 + u1;
                s_P[c & 1][lt][2][j] = c0 + c1;
            }
            __syncthreads();
        }
    } else {
        half2v wr[32], wu[32], wc[32];
#pragma unroll
        for (int m = 0; m < 32; ++m) {
            const int k = 64 + 2 * m;
            wr[m] = half2v{(_Float16)gk[(k + 0) * 128 + j], (_Float16)gk[(k + 1) * 128 + j]};
            wu[m] = half2v{(_Float16)gk[(k + 0) * 128 + 64 + j], (_Float16)gk[(k + 1) * 128 + 64 + j]};
            wc[m] = half2v{(_Float16)ck[(k + 0) * 64 + j], (_Float16)ck[(k + 1) * 64 + j]};
        }
        float h = 0.0f;
        for (int c = 0; c < nchunks; ++c) {
            __syncthreads();
            const int t0 = c * CC, tend = min(len, t0 + CC);
            for (int t = t0; t < tend; ++t) {
                const int lt = t - t0;
                const float pr = s_P[c & 1][lt][0][j];
                const float pu = s_P[c & 1][lt][1][j];
                const float pc = s_P[c & 1][lt][2][j];
                const float a  = arow[t];
                s_h[j] = (_Float16)h;
                wave_lds_fence();
                float r0 = pr, r1 = 0.f, u0 = pu, u1 = 0.f;
                const half8v* hv = (const half8v*)s_h;
#pragma unroll
                for (int m8 = 0; m8 < 8; ++m8) {
                    const half8v v = hv[m8];
                    const half2v p0 = __builtin_shufflevector(v, v, 0, 1);
                    const half2v p1 = __builtin_shufflevector(v, v, 2, 3);
                    const half2v p2 = __builtin_shufflevector(v, v, 4, 5);
                    const half2v p3 = __builtin_shufflevector(v, v, 6, 7);
                    const int m = m8 * 4;
                    r0 = __builtin_amdgcn_fdot2(p0, wr[m + 0], r0, false);
                    r1 = __builtin_amdgcn_fdot2(p1, wr[m + 1], r1, false);
                    r0 = __builtin_amdgcn_fdot2(p2, wr[m + 2], r0, false);
                    r1 = __builtin_amdgcn_fdot2(p3, wr[m + 3], r1, false);
                    u0 = __builtin_amdgcn_fdot2(p0, wu[m + 0], u0, false);
                    u1 = __builtin_amdgcn_fdot2(p1, wu[m + 1], u1, false);
                    u0 = __builtin_amdgcn_fdot2(p2, wu[m + 2], u0, false);
                    u1 = __builtin_amdgcn_fdot2(p3, wu[m + 3], u1, false);
                }
                const float rg = fast_sigmoid(r0 + r1);
                const float ug = fast_sigmoid(u0 + u1);
                s_rh[j] = (_Float16)(rg * h);
                wave_lds_fence();
                float c0 = pc, c1 = 0.f;
                const half8v* rv = (const half8v*)s_rh;
#pragma unroll
                for (int m8 = 0; m8 < 8; ++m8) {
                    const half8v v = rv[m8];
                    const half2v p0 = __builtin_shufflevector(v, v, 0, 1);
                    const half2v p1 = __builtin_shufflevector(v, v, 2, 3);
                    const half2v p2 = __builtin_shufflevector(v, v, 4, 5);
                    const half2v p3 = __builtin_shufflevector(v, v, 6, 7);
                    const int m = m8 * 4;
                    c0 = __builtin_amdgcn_fdot2(p0, wc[m + 0], c0, false);
                    c1 = __builtin_amdgcn_fdot2(p1, wc[m + 1], c1, false);
                    c0 = __builtin_amdgcn_fdot2(p2, wc[m + 2], c0, false);
                    c1 = __builtin_amdgcn_fdot2(p3, wc[m + 3], c1, false);
                }
                const float cg = fast_tanh(c0 + c1);
                const float uh = (1.0f - a) * ug;
                h = uh * h + (1.0f - uh) * cg;
                orow[t * Hn + j] = h;
                wave_lds_fence();
            }
        }
    }
    float4 z; z.x = z.y = z.z = z.w = 0.0f;
    float* tail = orow + len * Hn;
    const int total = (Tn - len) * Hn;
    for (int i = tid * 4; i < total; i += 128 * 4) *(float4*)(tail + i) = z;
}

extern "C" void kernel_launch(void* const* d_in, const int* in_sizes, int n_in,
                              void* d_out, int out_size, void* d_ws, size_t ws_size,
                              hipStream_t stream) {
    const float* x    = (const float*)d_in[0];
    const int*   slen = (const int*)  d_in[1];
    const float* att  = (const float*)d_in[2];
    const float* gk   = (const float*)d_in[3];
    const float* gb   = (const float*)d_in[4];
    const float* ck   = (const float*)d_in[5];
    const float* cb   = (const float*)d_in[6];
    float* out = (float*)d_out;

    const int B = in_sizes[1];  // 2048
    const size_t needP = (size_t)B * Tn * 192 * sizeof(_Float16);  // 157 MB

    if (ws_size >= needP) {
        _Float16* P = (_Float16*)d_ws;
        const int nrows = B * Tn;
        const int nsub  = nrows / 16;            // 25600, exact
        augru_proj_mfma<<<2048, 64, 0, stream>>>(x, slen, gk, gb, ck, cb, P, nsub);
        augru_rec<<<B, 64, 0, stream>>>(P, slen, att, gk, ck, out);
    } else {
        augru_fused_fb<<<B, 128, 0, stream>>>(x, slen, att, gk, gb, ck, cb, out);
    }
}

// Round 14
// 329.248 us; speedup vs baseline: 1.1369x; 1.1369x over previous
//
#include <hip/hip_runtime.h>

#define Tn 200
#define Dn 64
#define Hn 64
#define CC 16   // chunk size for fallback kernel

typedef _Float16 half2v __attribute__((ext_vector_type(2)));
typedef _Float16 half8v __attribute__((ext_vector_type(8)));
typedef float    f32x4  __attribute__((ext_vector_type(4)));
typedef unsigned int uint;

__device__ __forceinline__ float fast_sigmoid(float v) {
    return __builtin_amdgcn_rcpf(1.0f + __expf(-v));
}
__device__ __forceinline__ float fast_tanh(float v) {
    return 1.0f - 2.0f * __builtin_amdgcn_rcpf(1.0f + __expf(2.0f * v));
}
// Compiler-only fence (R7-verified): intra-wave DS ordering is HW in-order.
__device__ __forceinline__ void cfence() {
    asm volatile("" ::: "memory");
}
// Full fence for the multi-wave fallback kernel (cross-wave LDS ordering).
__device__ __forceinline__ void wave_lds_fence() {
    asm volatile("s_waitcnt lgkmcnt(0)" ::: "memory");
}

__device__ __forceinline__ half8v cvt8(const float4 a, const float4 b) {
    return half8v{(_Float16)a.x, (_Float16)a.y, (_Float16)a.z, (_Float16)a.w,
                  (_Float16)b.x, (_Float16)b.y, (_Float16)b.z, (_Float16)b.w};
}

// ============================================================================
// Kernel 1 (R13-verified, ~59 us): x-projection GEMM, one WAVE per 16-row
// subtile, grid 2048 (12.5 subtiles/wave: weight-init amortized, waves fully
// resident) + 1-deep A-prefetch pipeline (next subtile's loads issued before
// computing current -> load latency hides under MFMA+LDS+stores).
// ============================================================================
__global__ __launch_bounds__(64, 1)
void augru_proj_mfma(const float* __restrict__ x,     // [B*T, 64]
                     const int*   __restrict__ slen,  // [B]
                     const float* __restrict__ gk,    // [128][128]
                     const float* __restrict__ gb,    // [128]
                     const float* __restrict__ ck,    // [128][64]
                     const float* __restrict__ cb,    // [64]
                     _Float16*    __restrict__ P,     // [B*T, 192] fp16
                     int nsub)                        // nrows / 16
{
    const int lane = threadIdx.x;
    const int lm   = lane & 15;     // M (A) / N (B) index inside fragment
    const int kq   = lane >> 4;     // K quadrant
    const int G    = gridDim.x;

    __shared__ __align__(16) _Float16 sbuf[16][200];  // 6.4 KB, 400B row stride

    // ---- persistent B-frags + biases: 12 col-tiles x 2 K-halves ----
    half8v bf[12][2];
    float  bias[12];
#pragma unroll
    for (int nt = 0; nt < 12; ++nt) {
        const int n = nt * 16 + lm;
#pragma unroll
        for (int kh = 0; kh < 2; ++kh) {
            half8v f;
#pragma unroll
            for (int e = 0; e < 8; ++e) {
                const int k = kh * 32 + kq * 8 + e;
                f[e] = (_Float16)((n < 128) ? gk[k * 128 + n]
                                            : ck[k * 64 + (n - 128)]);
            }
            bf[nt][kh] = f;
        }
        bias[nt] = (n < 128) ? gb[n] : cb[n - 128];
    }

    // ---- prologue: load A for first assigned subtile ----
    float4 qa0{}, qa1{}, qa2{}, qa3{};
    if (blockIdx.x < nsub) {
        const float* xr = x + (size_t)(blockIdx.x * 16 + lm) * Dn + kq * 8;
        qa0 = *(const float4*)(xr);
        qa1 = *(const float4*)(xr + 4);
        qa2 = *(const float4*)(xr + 32);
        qa3 = *(const float4*)(xr + 36);
    }

    for (int s = blockIdx.x; s < nsub; s += G) {
        // ---- issue next subtile's A loads (1-deep pipeline) ----
        float4 qb0{}, qb1{}, qb2{}, qb3{};
        const int sn = s + G;
        if (sn < nsub) {
            const float* xr = x + (size_t)(sn * 16 + lm) * Dn + kq * 8;
            qb0 = *(const float4*)(xr);
            qb1 = *(const float4*)(xr + 4);
            qb2 = *(const float4*)(xr + 32);
            qb3 = *(const float4*)(xr + 36);
        }

        // ---- subtile validity (lane lm checks row rb+lm) ----
        const int rb   = s * 16;
        const int rowv = rb + lm;
        const int bv   = rowv / Tn;
        const int tv   = rowv - bv * Tn;
        if (__ballot(tv < slen[bv]) != 0ull) {
            const half8v a0 = cvt8(qa0, qa1);   // k = 0..31
            const half8v a1 = cvt8(qa2, qa3);   // k = 32..63

            // MFMA all 12 tiles; fragments -> LDS (row=kq*4+r, col=nt*16+lm)
#pragma unroll
            for (int nt = 0; nt < 12; ++nt) {
                f32x4 c = {bias[nt], bias[nt], bias[nt], bias[nt]};
                c = __builtin_amdgcn_mfma_f32_16x16x32_f16(a0, bf[nt][0], c, 0, 0, 0);
                c = __builtin_amdgcn_mfma_f32_16x16x32_f16(a1, bf[nt][1], c, 0, 0, 0);
#pragma unroll
                for (int r = 0; r < 4; ++r)
                    sbuf[kq * 4 + r][nt * 16 + lm] = (_Float16)c[r];
            }
            cfence();   // same-wave DS in-order; pin compiler order

            // coalesced store: 6 x dwordx4 per lane (16 rows x 384 B)
#pragma unroll
            for (int i = 0; i < 6; ++i) {
                const int idx = i * 64 + lane;   // 0..383
                const int row = idx / 24;        // 24 x 16B chunks per row
                const int c16 = idx % 24;
                const uint4 v = *(const uint4*)&sbuf[row][c16 * 8];
                *(uint4*)(P + (size_t)(rb + row) * 192 + c16 * 8) = v;
            }
            cfence();   // WAR vs next subtile's LDS writes (in-order pipe)
        }

        qa0 = qb0; qa1 = qb1; qa2 = qb2; qa3 = qb3;
    }
}

// ============================================================================
// Kernel 2 (R12-verified, 136 us, VGPR 104): recurrence, 1 wave per row.
// R13's hoist+4-chain variant regressed (VGPR 68: allocator remat'd the
// weight arrays to chase occupancy). This is the byte-exact R12 form --
// keep the live set where 104 VGPRs sufficed.
// ============================================================================
__global__ __launch_bounds__(64, 2)
void augru_rec(const _Float16* __restrict__ P,   // [B,T,3,64] fp16
               const int*     __restrict__ slen, // [B]
               const float*   __restrict__ att,  // [B,T]
               const float*   __restrict__ gk,   // [128][128]
               const float*   __restrict__ ck,   // [128][64]
               float*         __restrict__ out)  // [B,T,H]
{
    const int b = blockIdx.x;
    const int j = threadIdx.x;

    __shared__ __align__(16) _Float16 s_h[Hn];
    __shared__ __align__(16) _Float16 s_rh[Hn];

    half2v wr[32], wu[32], wc[32];   // h-part weight cols (K rows 64..127)
#pragma unroll
    for (int m = 0; m < 32; ++m) {
        const int k = 64 + 2 * m;
        wr[m] = half2v{(_Float16)gk[(k + 0) * 128 + j],
                       (_Float16)gk[(k + 1) * 128 + j]};
        wu[m] = half2v{(_Float16)gk[(k + 0) * 128 + 64 + j],
                       (_Float16)gk[(k + 1) * 128 + 64 + j]};
        wc[m] = half2v{(_Float16)ck[(k + 0) * 64 + j],
                       (_Float16)ck[(k + 1) * 64 + j]};
    }

    const int len = slen[b];
    const _Float16* Prow = P   + (size_t)b * Tn * 192;
    const float*    arow = att + (size_t)b * Tn;
    float*          orow = out + (size_t)b * Tn * Hn;

    float h = 0.0f;

    _Float16 pr_n = (_Float16)0, pu_n = (_Float16)0, pc_n = (_Float16)0;
    float a_n = 0.0f;
    if (len > 0) {
        pr_n = Prow[j]; pu_n = Prow[64 + j]; pc_n = Prow[128 + j];
        a_n  = arow[0];
    }

    for (int t = 0; t < len; ++t) {
        const float pr = (float)pr_n;    // loaded last iteration
        const float pu = (float)pu_n;
        const float pc = (float)pc_n;
        const float a  = a_n;
        const int tn = min(t + 1, len - 1);
        const _Float16* Pt = Prow + (size_t)tn * 192;
        pr_n = Pt[j]; pu_n = Pt[64 + j]; pc_n = Pt[128 + j];
        a_n  = arow[tn];

        s_h[j] = (_Float16)h;
        cfence();   // order only; HW DS pipe is in-order within the wave

        float r0 = pr, r1 = 0.f, u0 = pu, u1 = 0.f;
        const half8v* hv = (const half8v*)s_h;   // 8 x 16B broadcast reads
#pragma unroll
        for (int m8 = 0; m8 < 8; ++m8) {
            const half8v v = hv[m8];
            const half2v p0 = __builtin_shufflevector(v, v, 0, 1);
            const half2v p1 = __builtin_shufflevector(v, v, 2, 3);
            const half2v p2 = __builtin_shufflevector(v, v, 4, 5);
            const half2v p3 = __builtin_shufflevector(v, v, 6, 7);
            const int m = m8 * 4;
            r0 = __builtin_amdgcn_fdot2(p0, wr[m + 0], r0, false);
            r1 = __builtin_amdgcn_fdot2(p1, wr[m + 1], r1, false);
            r0 = __builtin_amdgcn_fdot2(p2, wr[m + 2], r0, false);
            r1 = __builtin_amdgcn_fdot2(p3, wr[m + 3], r1, false);
            u0 = __builtin_amdgcn_fdot2(p0, wu[m + 0], u0, false);
            u1 = __builtin_amdgcn_fdot2(p1, wu[m + 1], u1, false);
            u0 = __builtin_amdgcn_fdot2(p2, wu[m + 2], u0, false);
            u1 = __builtin_amdgcn_fdot2(p3, wu[m + 3], u1, false);
        }
        const float rg = fast_sigmoid(r0 + r1);
        const float ug = fast_sigmoid(u0 + u1);

        s_rh[j] = (_Float16)(rg * h);
        cfence();

        float c0 = pc, c1 = 0.f;
        const half8v* rv = (const half8v*)s_rh;
#pragma unroll
        for (int m8 = 0; m8 < 8; ++m8) {
            const half8v v = rv[m8];
            const half2v p0 = __builtin_shufflevector(v, v, 0, 1);
            const half2v p1 = __builtin_shufflevector(v, v, 2, 3);
            const half2v p2 = __builtin_shufflevector(v, v, 4, 5);
            const half2v p3 = __builtin_shufflevector(v, v, 6, 7);
            const int m = m8 * 4;
            c0 = __builtin_amdgcn_fdot2(p0, wc[m + 0], c0, false);
            c1 = __builtin_amdgcn_fdot2(p1, wc[m + 1], c1, false);
            c0 = __builtin_amdgcn_fdot2(p2, wc[m + 2], c0, false);
            c1 = __builtin_amdgcn_fdot2(p3, wc[m + 3], c1, false);
        }
        const float cg = fast_tanh(c0 + c1);

        const float uh = (1.0f - a) * ug;
        h = uh * h + (1.0f - uh) * cg;
        orow[t * Hn + j] = h;
        cfence();   // WAR vs next t's s_h/s_rh writes: HW in-order, compiler pinned
    }

    // ---- zero tail: out[b, len:T, :] = 0 ----
    float4 z;
    z.x = z.y = z.z = z.w = 0.0f;
    float* tail = orow + (size_t)len * Hn;
    const int total = (Tn - len) * Hn;
    for (int i = j * 4; i < total; i += 64 * 4) {
        *(float4*)(tail + i) = z;
    }
}

// ============================================================================
// Fallback (fused) if ws is too small for P. (unchanged)
// ============================================================================
__global__ __launch_bounds__(128, 2)
void augru_fused_fb(const float* __restrict__ x, const int* __restrict__ slen,
                    const float* __restrict__ att, const float* __restrict__ gk,
                    const float* __restrict__ gb, const float* __restrict__ ck,
                    const float* __restrict__ cb, float* __restrict__ out)
{
    const int b    = blockIdx.x;
    const int tid  = threadIdx.x;
    const int wave = tid >> 6;
    const int j    = tid & 63;

    __shared__ float s_P[2][CC][3][Hn];
    __shared__ __align__(16) _Float16 s_h[Hn];
    __shared__ __align__(16) _Float16 s_rh[Hn];

    const int len     = slen[b];
    const int nchunks = (len + CC - 1) / CC;
    const float* xrow = x   + (size_t)b * Tn * Dn;
    const float* arow = att + (size_t)b * Tn;
    float*       orow = out + (size_t)b * Tn * Hn;

    if (wave == 0) {
        half2v wr[32], wu[32], wc[32];
#pragma unroll
        for (int m = 0; m < 32; ++m) {
            const int k = 2 * m;
            wr[m] = half2v{(_Float16)gk[(k + 0) * 128 + j], (_Float16)gk[(k + 1) * 128 + j]};
            wu[m] = half2v{(_Float16)gk[(k + 0) * 128 + 64 + j], (_Float16)gk[(k + 1) * 128 + 64 + j]};
            wc[m] = half2v{(_Float16)ck[(k + 0) * 64 + j], (_Float16)ck[(k + 1) * 64 + j]};
        }
        const float br = gb[j], bu = gb[64 + j], bc = cb[j];
        for (int c = 0; c < nchunks; ++c) {
            const int t0 = c * CC, tend = min(len, t0 + CC);
            for (int t = t0; t < tend; ++t) {
                const float4* xv = (const float4*)(xrow + t * Dn);
                float r0 = br, r1 = 0.f, u0 = bu, u1 = 0.f, c0 = bc, c1 = 0.f;
#pragma unroll
                for (int kk = 0; kk < 16; ++kk) {
                    const float4 q = xv[kk];
                    const half2v p0 = half2v{(_Float16)q.x, (_Float16)q.y};
                    const half2v p1 = half2v{(_Float16)q.z, (_Float16)q.w};
                    const int m = 2 * kk;
                    r0 = __builtin_amdgcn_fdot2(p0, wr[m], r0, false);
                    r1 = __builtin_amdgcn_fdot2(p1, wr[m + 1], r1, false);
                    u0 = __builtin_amdgcn_fdot2(p0, wu[m], u0, false);
                    u1 = __builtin_amdgcn_fdot2(p1, wu[m + 1], u1, false);
                    c0 = __builtin_amdgcn_fdot2(p0, wc[m], c0, false);
                    c1 = __builtin_amdgcn_fdot2(p1, wc[m + 1], c1, false);
                }
                const int lt = t - t0;
                s_P[c & 1][lt][0][j] = r0 + r1;
                s_P[c & 1][lt][1][j] = u0 + u1;
                s_P[c & 1][lt][2][j] = c0 + c1;
            }
            __syncthreads();
        }
    } else {
        half2v wr[32], wu[32], wc[32];
#pragma unroll
        for (int m = 0; m < 32; ++m) {
            const int k = 64 + 2 * m;
            wr[m] = half2v{(_Float16)gk[(k + 0) * 128 + j], (_Float16)gk[(k + 1) * 128 + j]};
            wu[m] = half2v{(_Float16)gk[(k + 0) * 128 + 64 + j], (_Float16)gk[(k + 1) * 128 + 64 + j]};
            wc[m] = half2v{(_Float16)ck[(k + 0) * 64 + j], (_Float16)ck[(k + 1) * 64 + j]};
        }
        float h = 0.0f;
        for (int c = 0; c < nchunks; ++c) {
            __syncthreads();
            const int t0 = c * CC, tend = min(len, t0 + CC);
            for (int t = t0; t < tend; ++t) {
                const int lt = t - t0;
                const float pr = s_P[c & 1][lt][0][j];
                const float pu = s_P[c & 1][lt][1][j];
                const float pc = s_P[c & 1][lt][2][j];
                const float a  = arow[t];
                s_h[j] = (_Float16)h;
                wave_lds_fence();
                float r0 = pr, r1 = 0.f, u0 = pu, u1 = 0.f;
                const half8v* hv = (const half8v*)s_h;
#pragma unroll
                for (int m8 = 0; m8 < 8; ++m8) {
                    const half8v v = hv[m8];
                    const half2v p0 = __builtin_shufflevector(v, v, 0, 1);
                    const half2v p1 = __builtin_shufflevector(v, v, 2, 3);
                    const half2v p2 = __builtin_shufflevector(v, v, 4, 5);
                    const half2v p3 = __builtin_shufflevector(v, v, 6, 7);
                    const int m = m8 * 4;
                    r0 = __builtin_amdgcn_fdot2(p0, wr[m + 0], r0, false);
                    r1 = __builtin_amdgcn_fdot2(p1, wr[m + 1], r1, false);
                    r0 = __builtin_amdgcn_fdot2(p2, wr[m + 2], r0, false);
                    r1 = __builtin_amdgcn_fdot2(p3, wr[m + 3], r1, false);
                    u0 = __builtin_amdgcn_fdot2(p0, wu[m + 0], u0, false);
                    u1 = __builtin_amdgcn_fdot2(p1, wu[m + 1], u1, false);
                    u0 = __builtin_amdgcn_fdot2(p2, wu[m + 2], u0, false);
                    u1 = __builtin_amdgcn_fdot2(p3, wu[m + 3], u1, false);
                }
                const float rg = fast_sigmoid(r0 + r1);
                const float ug = fast_sigmoid(u0 + u1);
                s_rh[j] = (_Float16)(rg * h);
                wave_lds_fence();
                float c0 = pc, c1 = 0.f;
                const half8v* rv = (const half8v*)s_rh;
#pragma unroll
                for (int m8 = 0; m8 < 8; ++m8) {
                    const half8v v = rv[m8];
                    const half2v p0 = __builtin_shufflevector(v, v, 0, 1);
                    const half2v p1 = __builtin_shufflevector(v, v, 2, 3);
                    const half2v p2 = __builtin_shufflevector(v, v, 4, 5);
                    const half2v p3 = __builtin_shufflevector(v, v, 6, 7);
                    const int m = m8 * 4;
                    c0 = __builtin_amdgcn_fdot2(p0, wc[m + 0], c0, false);
                    c1 = __builtin_amdgcn_fdot2(p1, wc[m + 1], c1, false);
                    c0 = __builtin_amdgcn_fdot2(p2, wc[m + 2], c0, false);
                    c1 = __builtin_amdgcn_fdot2(p3, wc[m + 3], c1, false);
                }
                const float cg = fast_tanh(c0 + c1);
                const float uh = (1.0f - a) * ug;
                h = uh * h + (1.0f - uh) * cg;
                orow[t * Hn + j] = h;
                wave_lds_fence();
            }
        }
    }
    float4 z; z.x = z.y = z.z = z.w = 0.0f;
    float* tail = orow + len * Hn;
    const int total = (Tn - len) * Hn;
    for (int i = tid * 4; i < total; i += 128 * 4) *(float4*)(tail + i) = z;
}

extern "C" void kernel_launch(void* const* d_in, const int* in_sizes, int n_in,
                              void* d_out, int out_size, void* d_ws, size_t ws_size,
                              hipStream_t stream) {
    const float* x    = (const float*)d_in[0];
    const int*   slen = (const int*)  d_in[1];
    const float* att  = (const float*)d_in[2];
    const float* gk   = (const float*)d_in[3];
    const float* gb   = (const float*)d_in[4];
    const float* ck   = (const float*)d_in[5];
    const float* cb   = (const float*)d_in[6];
    float* out = (float*)d_out;

    const int B = in_sizes[1];  // 2048
    const size_t needP = (size_t)B * Tn * 192 * sizeof(_Float16);  // 157 MB

    if (ws_size >= needP) {
        _Float16* P = (_Float16*)d_ws;
        const int nrows = B * Tn;
        const int nsub  = nrows / 16;            // 25600, exact
        augru_proj_mfma<<<2048, 64, 0, stream>>>(x, slen, gk, gb, ck, cb, P, nsub);
        augru_rec<<<B, 64, 0, stream>>>(P, slen, att, gk, ck, out);
    } else {
        augru_fused_fb<<<B, 128, 0, stream>>>(x, slen, att, gk, gb, ck, cb, out);
    }
}